// Round 6
// baseline (355.362 us; speedup 1.0000x reference)
//
#include <hip/hip_runtime.h>
#include <stdint.h>

// SNN-STDP on MI355X (gfx950).
//
// prep (one pass over the 80 MB image, the irreducible HBM cost):
//   xmask[t][b][w]   : i-bitmask of x (binary spikes)
//   csxPart[q][t][i] : per-octant column sums of x (integer-exact partials)
//   rowpop[t][b]     : row popcount of x (float)
// snn: 256 persistent blocks x 2 neurons, zero grid syncs, W in LDS.
//
// Exact-algebra structure (error class = fp reassociation only):
//  * forward I[b,n] = sum_{i:x=1} W[n,i] -- set-bit iteration over mask words.
//  * SAT fast path: dynamics pin every W entry at exactly 1.0f within ~8
//    steps (net dW drift ~ +1.5/step, per-column positive with margin; clip
//    at 1.0 exact in both ref and ours). Per-block ballot of (W==1.0f) after
//    each update enables I = rowpop[t][b] (exact: sum of ones), skipping the
//    forward + W reads; flips back if ever violated.
//  * LTP[n,i] = A+ * sum_{b:spk} pre[b,i]: spikes ~always dense -> use
//    colsum_pre - sum_{b:!spk} pre, cp = fmaf(.9,cp,csx) in registers;
//    minority b's (expected ~0) reconstruct pre by Horner over mask history.
//  * LTD[n,i] = A- * sum_b post[b,n]*x[b,i]: post of an always-spiker is
//    BITWISE q = fmaf(.9,q,1) (same fmaf recurrence), so
//    LTD = q*csx + sum_{post!=q}(post-q)*x, exceptions by exact compare
//    (expected ~6 pairs chip-wide, all from t=0 non-spikers; their deltas
//    decay by 0.9/step and stay tiny).

#define T_STEPS 100
#define BATCH   256
#define IN      784
#define NOUT    512
#define MW      25          // 32-bit i-mask words per (t,b) row
#define NQ      8           // batch octants in prep (800 blocks -> 3.1/CU)
#define QROWS   (BATCH / NQ)
#define THREADS 512

// ---------------------------------------------------------------------------
// prep: grid = (NQ, T) x 256 threads; block handles QROWS batch rows of one t.
// Scalar loads are wave-coalesced (lane l -> i = g*256 + tid, 256B segments).
// ---------------------------------------------------------------------------
__global__ __launch_bounds__(256) void prep_kernel(
    const float* __restrict__ image,
    uint32_t* __restrict__ xmask,
    float* __restrict__ csxPart,
    float* __restrict__ rowpop)
{
    const int t   = blockIdx.y;
    const int bq  = blockIdx.x;
    const int tid = threadIdx.x;
    const bool h3 = (tid + 768) < IN;   // tid < 16
    __shared__ uint32_t rc[QROWS];
    if (tid < QROWS) rc[tid] = 0u;
    __syncthreads();

    float cs[4] = {0.f, 0.f, 0.f, 0.f};

    for (int lb = 0; lb < QROWS; ++lb) {
        const int b = bq * QROWS + lb;
        const float* xrow = image + ((size_t)t * BATCH + b) * IN;
        float xv[4];
        xv[0] = xrow[tid];
        xv[1] = xrow[tid + 256];
        xv[2] = xrow[tid + 512];
        xv[3] = h3 ? xrow[tid + 768] : 0.0f;
        cs[0] += xv[0]; cs[1] += xv[1]; cs[2] += xv[2]; cs[3] += xv[3];

        unsigned long long bal[4];
        bal[0] = __ballot(xv[0] > 0.5f);
        bal[1] = __ballot(xv[1] > 0.5f);
        bal[2] = __ballot(xv[2] > 0.5f);
        bal[3] = __ballot(xv[3] > 0.5f);

        const size_t mbase = ((size_t)t * BATCH + b) * MW;
        if ((tid & 31) == 0) {
            #pragma unroll
            for (int g = 0; g < 4; ++g) {
                const int widx = ((g << 8) + tid) >> 5;
                if (widx < MW)
                    xmask[mbase + widx] = (uint32_t)(bal[g] >> (tid & 32));
            }
        }
        if ((tid & 63) == 0) {
            const uint32_t p = (uint32_t)(__popcll(bal[0]) + __popcll(bal[1]) +
                                          __popcll(bal[2]) + __popcll(bal[3]));
            atomicAdd(&rc[lb], p);
        }
    }
    __syncthreads();
    if (tid < QROWS)
        rowpop[(size_t)t * BATCH + bq * QROWS + tid] = (float)rc[tid];

    float* cb = csxPart + ((size_t)bq * T_STEPS + t) * IN;
    cb[tid]       = cs[0];
    cb[tid + 256] = cs[1];
    cb[tid + 512] = cs[2];
    if (h3) cb[tid + 768] = cs[3];
}

// ---------------------------------------------------------------------------
// Rare path: reconstruct updated pre-trace pre_t[b,{ip,ip+1}] by Horner over
// the global bitmask history. Expected calls ~0 (only t=0 non-spikers).
// ---------------------------------------------------------------------------
__device__ __forceinline__ float2 pre_reconstruct(
    const uint32_t* __restrict__ xg, int t, int bb, int wq, int sh)
{
    float p0 = 0.f, p1 = 0.f;
    for (int s = 0; s <= t; ++s) {
        const uint32_t w = xg[((size_t)s * BATCH + bb) * MW + wq];
        p0 = fmaf(0.9f, p0, (float)((w >> sh) & 1u));
        p1 = fmaf(0.9f, p1, (float)((w >> (sh + 1)) & 1u));
    }
    return make_float2(p0, p1);
}

// ---------------------------------------------------------------------------
// snn: persistent recurrence. Block owns neurons {2*bid, 2*bid+1}.
// Barriers/step: 2 when saturated, 3 otherwise. LDS ~10.5 KB static.
// ---------------------------------------------------------------------------
__global__ __launch_bounds__(THREADS, 1) void snn_kernel(
    const float* __restrict__ W_in,
    const uint32_t* __restrict__ xmask,
    const float* __restrict__ csxPart,
    const float* __restrict__ rowpop,
    float* __restrict__ out)
{
    __shared__ float2 Wpair[IN];          // (W[n0,i], W[n1,i])
    __shared__ float2 fpart[BATCH];       // seg1 forward partials (slow path)
    __shared__ uint32_t spkm0[8], spkm1[8], exm[8], satw[8];
    __shared__ float nldA[BATCH], nldB[BATCH];   // post - q

    const int tid = threadIdx.x;
    const int n0  = blockIdx.x * 2;
    const int b   = tid & 255;
    const int seg = tid >> 8;
    const bool act = (tid < IN / 2);      // 392 i-pair owners
    const int ip  = 2 * tid;
    const int wq  = ip >> 5, sh = ip & 31;

    for (int k = tid; k < IN; k += THREADS)
        Wpair[k] = make_float2(W_in[(size_t)n0 * IN + k],
                               W_in[(size_t)(n0 + 1) * IN + k]);
    if (tid < 8) satw[tid] = 0u;
    __syncthreads();

    float syn0 = 0.f, syn1 = 0.f, mem0 = 0.f, mem1 = 0.f;
    float sp0 = 0.f, sp1 = 0.f, post0 = 0.f, post1 = 0.f;
    float q = 0.f, cp0 = 0.f, cp1 = 0.f;

    for (int t = 0; t < T_STEPS; ++t) {
        // block-uniform saturation flag (from prev step's W-update ballot)
        const bool sat = (satw[0] & satw[1] & satw[2] & satw[3] &
                          satw[4] & satw[5] & satw[6] & satw[7]) != 0u;
        q = fmaf(0.9f, q, 1.0f);
        const bool have = (tid < BATCH);
        float I0 = 0.f, I1 = 0.f;

        if (sat) {
            // W all-ones: I = row popcount (exact; sum of 1.0f's)
            if (have) { const float rp = rowpop[(size_t)t * BATCH + b]; I0 = rp; I1 = rp; }
        } else {
            float a0 = 0.f, a1 = 0.f;
            const uint32_t* xrow = xmask + ((size_t)t * BATCH + b) * MW;  // L2-hot
            const int wlo = seg ? 13 : 0;
            const int whi = seg ? 25 : 13;
            for (int w = wlo; w < whi; ++w) {
                uint32_t m = xrow[w];
                const float2* bp = Wpair + (w << 5);
                while (m) {
                    const int k = __ffs(m) - 1;
                    m &= (m - 1u);
                    const float2 v = bp[k];
                    a0 += v.x; a1 += v.y;
                }
            }
            if (seg) fpart[b] = make_float2(a0, a1);
            __syncthreads();   // (slow only) partials ready
            if (have) { const float2 fp = fpart[b]; I0 = a0 + fp.x; I1 = a1 + fp.y; }
        }

        // ---- LIF state update + ballots (b-threads, waves 0..3) ----
        if (have) {
            syn0 = fmaf(0.9f, syn0, I0);
            mem0 = fmaf(0.8f, mem0, syn0) - sp0;   // reset = spk_{t-1}, thr=1
            sp0  = (mem0 > 1.0f) ? 1.f : 0.f;
            post0 = fmaf(0.9f, post0, sp0);
            syn1 = fmaf(0.9f, syn1, I1);
            mem1 = fmaf(0.8f, mem1, syn1) - sp1;
            sp1  = (mem1 > 1.0f) ? 1.f : 0.f;
            post1 = fmaf(0.9f, post1, sp1);
            nldA[b] = post0 - q;                   // exactly 0.0 for always-spikers
            nldB[b] = post1 - q;
            const unsigned long long bal0 = __ballot(sp0 > 0.5f);
            const unsigned long long bal1 = __ballot(sp1 > 0.5f);
            const unsigned long long bale = __ballot((post0 != q) || (post1 != q));
            if ((tid & 63) == 0) {
                const int w2 = tid >> 5;           // 0,2,4,6
                spkm0[w2]     = (uint32_t)bal0;
                spkm0[w2 + 1] = (uint32_t)(bal0 >> 32);
                spkm1[w2]     = (uint32_t)bal1;
                spkm1[w2 + 1] = (uint32_t)(bal1 >> 32);
                exm[w2]       = (uint32_t)bale;
                exm[w2 + 1]   = (uint32_t)(bale >> 32);
            }
        }
        __syncthreads();   // B1: state/ballots ready for dW

        // ---- dW + W update (act threads), then saturation ballot ----
        bool ok4 = true;
        if (act) {
            float csx0 = 0.f, csx1 = 0.f;          // integer-exact partial sums
            #pragma unroll
            for (int qq = 0; qq < NQ; ++qq) {
                const float2 c = *(const float2*)(
                    csxPart + ((size_t)qq * T_STEPS + t) * IN + ip);
                csx0 += c.x; csx1 += c.y;
            }
            cp0 = fmaf(0.9f, cp0, csx0);           // colsum-pre recurrence
            cp1 = fmaf(0.9f, cp1, csx1);

            int cnt0 = 0, cnt1 = 0;
            #pragma unroll
            for (int k = 0; k < 8; ++k) {
                cnt0 += __popc(spkm0[k]);
                cnt1 += __popc(spkm1[k]);
            }
            const bool comp0 = (cnt0 >= 128);
            const bool comp1 = (cnt1 >= 128);

            // LTP minority sums (expected empty)
            float sA0 = 0.f, sA1 = 0.f, sB0 = 0.f, sB1 = 0.f;
            #pragma unroll
            for (int k = 0; k < 8; ++k) {
                uint32_t m0 = comp0 ? ~spkm0[k] : spkm0[k];
                while (m0) {
                    const int j = __ffs(m0) - 1; m0 &= (m0 - 1u);
                    const float2 p = pre_reconstruct(xmask, t, (k << 5) + j, wq, sh);
                    sA0 += p.x; sA1 += p.y;
                }
                uint32_t m1 = comp1 ? ~spkm1[k] : spkm1[k];
                while (m1) {
                    const int j = __ffs(m1) - 1; m1 &= (m1 - 1u);
                    const float2 p = pre_reconstruct(xmask, t, (k << 5) + j, wq, sh);
                    sB0 += p.x; sB1 += p.y;
                }
            }
            const float ltpA0 = comp0 ? (cp0 - sA0) : sA0;   // (n0, ip)
            const float ltpA1 = comp0 ? (cp1 - sA1) : sA1;   // (n0, ip+1)
            const float ltpB0 = comp1 ? (cp0 - sB0) : sB0;   // (n1, ip)
            const float ltpB1 = comp1 ? (cp1 - sB1) : sB1;   // (n1, ip+1)

            // LTD = q*csx + exception corrections (expected ~6 chip-wide)
            float ltdA0 = q * csx0, ltdA1 = q * csx1;
            float ltdB0 = ltdA0,    ltdB1 = ltdA1;
            #pragma unroll
            for (int k = 0; k < 8; ++k) {
                uint32_t m = exm[k];
                while (m) {
                    const int j = __ffs(m) - 1; m &= (m - 1u);
                    const int eb = (k << 5) + j;
                    const uint32_t mw = xmask[((size_t)t * BATCH + eb) * MW + wq];
                    const float x0 = (float)((mw >> sh) & 1u);
                    const float x1 = (float)((mw >> (sh + 1)) & 1u);
                    const float d0 = nldA[eb], d1 = nldB[eb];
                    ltdA0 = fmaf(d0, x0, ltdA0);
                    ltdA1 = fmaf(d0, x1, ltdA1);
                    ltdB0 = fmaf(d1, x0, ltdB0);
                    ltdB1 = fmaf(d1, x1, ltdB1);
                }
            }

            float2 wa = Wpair[ip];        // (W[n0,ip],   W[n1,ip])
            float2 wb = Wpair[ip + 1];    // (W[n0,ip+1], W[n1,ip+1])
            wa.x += 0.008f * ltpA0 - 0.005f * ltdA0;
            wa.y += 0.008f * ltpB0 - 0.005f * ltdB0;
            wb.x += 0.008f * ltpA1 - 0.005f * ltdA1;
            wb.y += 0.008f * ltpB1 - 0.005f * ltdB1;
            wa.x = fminf(fmaxf(wa.x, 0.f), 1.f);
            wa.y = fminf(fmaxf(wa.y, 0.f), 1.f);
            wb.x = fminf(fmaxf(wb.x, 0.f), 1.f);
            wb.y = fminf(fmaxf(wb.y, 0.f), 1.f);
            Wpair[ip]     = wa;
            Wpair[ip + 1] = wb;
            ok4 = (wa.x == 1.0f) && (wa.y == 1.0f) &&
                  (wb.x == 1.0f) && (wb.y == 1.0f);
        }
        const unsigned long long okb = __ballot(ok4);
        if ((tid & 63) == 0) satw[tid >> 6] = (okb == ~0ull) ? 1u : 0u;
        __syncthreads();   // B2: W + satw settled before next step
    }

    if (act) {
        const float2 wa = Wpair[ip], wb = Wpair[ip + 1];
        *(float2*)(out + (size_t)n0 * IN + ip)       = make_float2(wa.x, wb.x);
        *(float2*)(out + (size_t)(n0 + 1) * IN + ip) = make_float2(wa.y, wb.y);
    }
}

// ---------------------------------------------------------------------------
extern "C" void kernel_launch(void* const* d_in, const int* in_sizes, int n_in,
                              void* d_out, int out_size, void* d_ws, size_t ws_size,
                              hipStream_t stream) {
    const float* image = (const float*)d_in[0];   // [100][256][784] f32
    const float* W_in  = (const float*)d_in[1];   // [512][784] f32
    float* out = (float*)d_out;                   // [512][784] f32

    char* p = (char*)d_ws;
    uint32_t* xmask = (uint32_t*)p;  p += (size_t)T_STEPS * BATCH * MW * 4;   // 2.56 MB
    float* csxPart  = (float*)p;     p += (size_t)NQ * T_STEPS * IN * 4;      // 2.51 MB
    float* rowpopw  = (float*)p;     // 100*256*4 = 102.4 KB; total ~5.2 MB

    prep_kernel<<<dim3(NQ, T_STEPS), 256, 0, stream>>>(image, xmask, csxPart, rowpopw);
    snn_kernel<<<NOUT / 2, THREADS, 0, stream>>>(W_in, xmask, csxPart, rowpopw, out);
}